// Round 12
// baseline (289.454 us; speedup 1.0000x reference)
//
#include <hip/hip_runtime.h>

// ---------------------------------------------------------------------------
// GAT 2-layer forward, round 12.
//  - fill fused into gemm0 dispatch (independent work, same-stream overlap)
//  - scan_bsum eliminated (scan_final self-computes its block offset)
//  - agg: R8/R10 proven structure - untouched. 7 kernel dispatches total.
// ---------------------------------------------------------------------------

typedef __attribute__((ext_vector_type(8))) short short8v;   // 8 bf16
typedef __attribute__((ext_vector_type(4))) float f32x4;

#define LOG2E 1.4426950408889634f

__device__ inline unsigned short f2bf(float x) {
    union { float f; unsigned int u; } v; v.f = x;
    unsigned int r = v.u + 0x7fffu + ((v.u >> 16) & 1u);   // RNE
    return (unsigned short)(r >> 16);
}
__device__ inline float bf2f(unsigned short h) {
    union { unsigned int u; float f; } v; v.u = ((unsigned int)h) << 16;
    return v.f;
}

// ---------------- GEMM tile body (shared by gemm_fused and gemm0_fill) ------
// C[M][N] = A[M][K] @ Bt[N][K]^T, A bf16. Tile 128x128, BK=64, 256 thr, 4 waves.
template<int H>
__device__ __forceinline__ void gemm_tile(
    const unsigned short* __restrict__ A, const unsigned short* __restrict__ Bt,
    unsigned short* __restrict__ C,
    const float* __restrict__ al, const float* __restrict__ ar,
    float* __restrict__ el, float* __restrict__ er,
    int M, int N, int K, int bx, int by)
{
    __shared__ __align__(16) unsigned short As[128 * 64];
    __shared__ __align__(16) unsigned short Bs[128 * 64];
    const int tid = threadIdx.x;
    const int lane = tid & 63, wv = tid >> 6;
    const int rowBase = bx * 128;
    const int colBase = by * 128;

    f32x4 acc[2][8];
    #pragma unroll
    for (int i = 0; i < 2; ++i)
        #pragma unroll
        for (int j = 0; j < 8; ++j)
            acc[i][j] = (f32x4){0.f, 0.f, 0.f, 0.f};

    for (int k0 = 0; k0 < K; k0 += 64) {
        #pragma unroll
        for (int c = tid; c < 128 * 8; c += 256) {
            int row = c >> 3, cc = c & 7;
            int gr = rowBase + row; if (gr >= M) gr = M - 1;
            int4 v = *(const int4*)(A + (size_t)gr * K + k0 + cc * 8);
            *(int4*)&As[row * 64 + (cc ^ (row & 7)) * 8] = v;
        }
        #pragma unroll
        for (int c = tid; c < 128 * 8; c += 256) {
            int n2 = c >> 3, cc = c & 7;
            int4 v = *(const int4*)(Bt + (size_t)(colBase + n2) * K + k0 + cc * 8);
            *(int4*)&Bs[n2 * 64 + (cc ^ (n2 & 7)) * 8] = v;
        }
        __syncthreads();

        #pragma unroll
        for (int ks = 0; ks < 64; ks += 32) {
            int kchunk = (ks >> 3) + (lane >> 4);   // 0..7
            short8v af[2], bfr[8];
            #pragma unroll
            for (int fm = 0; fm < 2; ++fm) {
                int ml = wv * 32 + fm * 16 + (lane & 15);
                af[fm] = *(const short8v*)&As[ml * 64 + (kchunk ^ (ml & 7)) * 8];
            }
            #pragma unroll
            for (int fi = 0; fi < 8; ++fi) {
                int nl = fi * 16 + (lane & 15);
                bfr[fi] = *(const short8v*)&Bs[nl * 64 + (kchunk ^ (nl & 7)) * 8];
            }
            #pragma unroll
            for (int fm = 0; fm < 2; ++fm)
                #pragma unroll
                for (int fi = 0; fi < 8; ++fi)
                    acc[fm][fi] = __builtin_amdgcn_mfma_f32_16x16x32_bf16(
                        af[fm], bfr[fi], acc[fm][fi], 0, 0, 0);
        }
        __syncthreads();
    }

    float alv[8], arv[8];
    #pragma unroll
    for (int fi = 0; fi < 8; ++fi) {
        int col = colBase + fi * 16 + (lane & 15);
        alv[fi] = al[col];
        arv[fi] = ar[col];
    }
    const int head = (H == 2) ? by : 0;

    #pragma unroll
    for (int fm = 0; fm < 2; ++fm) {
        #pragma unroll
        for (int r = 0; r < 4; ++r) {
            int row = rowBase + wv * 32 + fm * 16 + (lane >> 4) * 4 + r;
            float pe = 0.f, pr2 = 0.f;
            #pragma unroll
            for (int fi = 0; fi < 8; ++fi) {
                pe  = fmaf(acc[fm][fi][r], alv[fi], pe);
                pr2 = fmaf(acc[fm][fi][r], arv[fi], pr2);
            }
            #pragma unroll
            for (int off = 8; off; off >>= 1) {
                pe  += __shfl_xor(pe, off);
                pr2 += __shfl_xor(pr2, off);
            }
            if (row < M) {
                #pragma unroll
                for (int fi = 0; fi < 8; ++fi) {
                    int col = colBase + fi * 16 + (lane & 15);
                    C[(size_t)row * N + col] = f2bf(acc[fm][fi][r]);
                }
                if ((lane & 15) == 0) {
                    atomicAdd(&el[row * H + head], pe);
                    atomicAdd(&er[row * H + head], pr2);
                }
            }
        }
    }
}

template<int H>
__global__ __launch_bounds__(256) void gemm_fused(
    const unsigned short* __restrict__ A, const unsigned short* __restrict__ Bt,
    unsigned short* __restrict__ C,
    const float* __restrict__ al, const float* __restrict__ ar,
    float* __restrict__ el, float* __restrict__ er,
    int M, int N, int K)
{
    gemm_tile<H>(A, Bt, C, al, ar, el, er, M, N, K, blockIdx.x, blockIdx.y);
}

// gemm0 + fill fused: blocks [0,nbG) = gemm tiles (bid>>1 = row tile, shared
// A-tile between consecutive blocks), blocks [nbG,..) = CSR fill.
__global__ __launch_bounds__(256) void gemm0_fill(
    const unsigned short* __restrict__ A, const unsigned short* __restrict__ Bt,
    unsigned short* __restrict__ C,
    const float* __restrict__ al, const float* __restrict__ ar,
    float* __restrict__ el, float* __restrict__ er,
    int M, int N, int K, int nbG,
    const int* __restrict__ src, const int* __restrict__ dst,
    int* __restrict__ cursor, int* __restrict__ srcc, int E)
{
    int bid = blockIdx.x;
    if (bid < nbG) {
        gemm_tile<2>(A, Bt, C, al, ar, el, er, M, N, K, bid >> 1, bid & 1);
    } else {
        int t = (bid - nbG) * 256 + threadIdx.x;
        if (t < E) {
            int pos = atomicAdd(&cursor[dst[t]], 1);
            srcc[pos] = src[t];
        }
    }
}

// ---------------- fused weight-convert + emb-convert + count ----------------
__global__ void conv_count(const float* __restrict__ W0, unsigned short* __restrict__ W0t,
                           const float* __restrict__ W1, unsigned short* __restrict__ W1t,
                           const float* __restrict__ emb, unsigned short* __restrict__ embb,
                           const int* __restrict__ dst, int* __restrict__ cnt,
                           int nbW, int nbE, int E, int nEmb)
{
    int bid = blockIdx.x;
    if (bid < nbW) {
        int t = bid * 256 + threadIdx.x;
        if (t < 128 * 256) {
            int k = t >> 8, n2 = t & 255;
            W0t[n2 * 128 + k] = f2bf(W0[t]);
        }
        int u = t - 128 * 256;
        if (u >= 0 && u < 256 * 256) {
            int k = u >> 8, n2 = u & 255;
            W1t[n2 * 256 + k] = f2bf(W1[u]);
        }
    } else if (bid < nbW + nbE) {
        int t = (bid - nbW) * 256 + threadIdx.x;
        if (t < E) atomicAdd(&cnt[dst[t]], 1);
    } else {
        int t = ((bid - nbW - nbE) * 256 + threadIdx.x) * 4;
        if (t + 3 < nEmb) {
            float4 v = *(const float4*)(emb + t);
            ushort4 o;
            o.x = f2bf(v.x); o.y = f2bf(v.y); o.z = f2bf(v.z); o.w = f2bf(v.w);
            *(ushort4*)(embb + t) = o;
        }
    }
}

__global__ __launch_bounds__(256) void scan_partial(const int* __restrict__ cnt,
                                                    int* __restrict__ bsum, int n)
{
    int t = threadIdx.x;
    int idx = blockIdx.x * 1024 + t * 4;
    int4 v = make_int4(0, 0, 0, 0);
    if (idx + 3 < n) v = *(const int4*)(cnt + idx);
    else if (idx < n) {
        v.x = cnt[idx];
        if (idx + 1 < n) v.y = cnt[idx + 1];
        if (idx + 2 < n) v.z = cnt[idx + 2];
    }
    int s = v.x + v.y + v.z + v.w;
    #pragma unroll
    for (int off = 32; off; off >>= 1) s += __shfl_xor(s, off);
    __shared__ int ws[4];
    if ((t & 63) == 0) ws[t >> 6] = s;
    __syncthreads();
    if (t == 0) bsum[blockIdx.x] = ws[0] + ws[1] + ws[2] + ws[3];
}

// scan_final: self-computes block offset from RAW bsum (wave-0 prefix scan),
// writes row/cursor, zeroes el0/er0, block 0 writes row[n]=E.
__global__ __launch_bounds__(256) void scan_final(
    const int* __restrict__ cnt, const int* __restrict__ bsum,
    int* __restrict__ row, int* __restrict__ cursor,
    float* __restrict__ el0, float* __restrict__ er0,
    int n, int nb, int E)
{
    int t = threadIdx.x;
    int lane = t & 63;
    __shared__ int blockOff;
    if (t < 64) {
        int v = (t < nb) ? bsum[t] : 0;
        int x = v;
        #pragma unroll
        for (int off = 1; off < 64; off <<= 1) {
            int y = __shfl_up(x, off);
            if (lane >= off) x += y;
        }
        if (t == (int)blockIdx.x) blockOff = x - v;   // exclusive prefix
    }
    if (blockIdx.x == 0 && t == 0) row[n] = E;

    int idx = blockIdx.x * 1024 + t * 4;
    int4 v = make_int4(0, 0, 0, 0);
    if (idx + 3 < n) v = *(const int4*)(cnt + idx);
    else if (idx < n) {
        v.x = cnt[idx];
        if (idx + 1 < n) v.y = cnt[idx + 1];
        if (idx + 2 < n) v.z = cnt[idx + 2];
    }
    int s1 = v.x + v.y, s2 = s1 + v.z, s3 = s2 + v.w;
    int tsum = s3;
    int x = tsum;
    #pragma unroll
    for (int off = 1; off < 64; off <<= 1) {
        int y = __shfl_up(x, off);
        if (lane >= off) x += y;
    }
    int wex = x - tsum;
    __shared__ int ws[4];
    if (lane == 63) ws[t >> 6] = x;
    __syncthreads();
    int off0 = blockOff;
    for (int w2 = 0; w2 < (t >> 6); ++w2) off0 += ws[w2];
    int e0 = off0 + wex;
    float2 z2 = make_float2(0.f, 0.f);
    if (idx < n)     { row[idx]     = e0;        cursor[idx]     = e0;
                       *(float2*)(el0 + 2*idx)     = z2; *(float2*)(er0 + 2*idx)     = z2; }
    if (idx + 1 < n) { row[idx + 1] = e0 + v.x;  cursor[idx + 1] = e0 + v.x;
                       *(float2*)(el0 + 2*idx + 2) = z2; *(float2*)(er0 + 2*idx + 2) = z2; }
    if (idx + 2 < n) { row[idx + 2] = e0 + s1;   cursor[idx + 2] = e0 + s1;
                       *(float2*)(el0 + 2*idx + 4) = z2; *(float2*)(er0 + 2*idx + 4) = z2; }
    if (idx + 3 < n) { row[idx + 3] = e0 + s2;   cursor[idx + 3] = e0 + s2;
                       *(float2*)(el0 + 2*idx + 6) = z2; *(float2*)(er0 + 2*idx + 6) = z2; }
}

// ---------------- per-dst-node softmax + weighted gather (R8 structure) ------
template<int H>
__global__ __launch_bounds__(256) void agg_kernel(
    const unsigned short* __restrict__ h, const float* __restrict__ el,
    const float* __restrict__ er, float* __restrict__ ecsr,
    const int* __restrict__ srcc, const int* __restrict__ row,
    const float* __restrict__ bias, float* __restrict__ outf,
    unsigned short* __restrict__ outb,
    float* __restrict__ elz, float* __restrict__ erz,
    int n_nodes, int E, int do_relu, int zero0)
{
    int wid = blockIdx.x * 4 + (threadIdx.x >> 6);
    if (wid >= n_nodes) return;
    int lane = threadIdx.x & 63;
    int beg = __builtin_amdgcn_readfirstlane(row[wid]);
    int end = __builtin_amdgcn_readfirstlane(row[wid + 1]);
    const int hsel   = (H == 2) ? (lane >> 5) : 0;
    const int stride = (H == 2) ? 32 : 64;
    const int l0     = (H == 2) ? (lane & 31) : lane;
    float* plane = ecsr + (size_t)hsel * E;
    const float rr = er[wid * H + hsel];

    if (elz && lane == 0) { elz[wid] = 0.f; erz[wid] = 0.f; }

    // stats pass: gather el[src], leaky, prescale by log2e, write plane, online m/s
    float m = -1e30f, s = 0.f;
    for (int i = beg + l0; i < end; i += stride) {
        int sn = srcc[i];
        float v = el[sn * H + hsel] + rr;
        float ev = ((v > 0.f) ? v : 0.2f * v) * LOG2E;
        plane[i] = ev;
        float mn = fmaxf(m, ev);
        s = s * exp2f(m - mn) + exp2f(ev - mn);
        m = mn;
    }
    #pragma unroll
    for (int off = (H == 2) ? 16 : 32; off; off >>= 1) {
        float mo = __shfl_xor(m, off);
        float so = __shfl_xor(s, off);
        float mn = fmaxf(m, mo);
        s = s * exp2f(m - mn) + so * exp2f(mo - mn);
        m = mn;
    }
    float r = (s > 0.f) ? 1.f / s : 0.f;
    __threadfence_block();

    // un-normalized weighted gather (x 1/s at the end), unroll 4
    float aA0 = 0.f, aA1 = 0.f, aA2 = 0.f, aA3 = 0.f;
    float aB0 = 0.f, aB1 = 0.f, aB2 = 0.f, aB3 = 0.f;
    float aC0 = 0.f, aC1 = 0.f, aC2 = 0.f, aC3 = 0.f;
    float aD0 = 0.f, aD1 = 0.f, aD2 = 0.f, aD3 = 0.f;
    int i = beg;
    for (; i + 3 < end; i += 4) {
        float wa = exp2f(plane[i]     - m);
        float wb = exp2f(plane[i + 1] - m);
        float wc = exp2f(plane[i + 2] - m);
        float wd = exp2f(plane[i + 3] - m);
        int sa = srcc[i], sb = srcc[i + 1], sc2 = srcc[i + 2], sd = srcc[i + 3];
        ushort4 ha = *(const ushort4*)(h + (size_t)sa * 256 + lane * 4);
        ushort4 hb = *(const ushort4*)(h + (size_t)sb * 256 + lane * 4);
        ushort4 hc = *(const ushort4*)(h + (size_t)sc2 * 256 + lane * 4);
        ushort4 hd = *(const ushort4*)(h + (size_t)sd * 256 + lane * 4);
        aA0 = fmaf(wa, bf2f(ha.x), aA0); aB0 = fmaf(wb, bf2f(hb.x), aB0);
        aC0 = fmaf(wc, bf2f(hc.x), aC0); aD0 = fmaf(wd, bf2f(hd.x), aD0);
        aA1 = fmaf(wa, bf2f(ha.y), aA1); aB1 = fmaf(wb, bf2f(hb.y), aB1);
        aC1 = fmaf(wc, bf2f(hc.y), aC1); aD1 = fmaf(wd, bf2f(hd.y), aD1);
        aA2 = fmaf(wa, bf2f(ha.z), aA2); aB2 = fmaf(wb, bf2f(hb.z), aB2);
        aC2 = fmaf(wc, bf2f(hc.z), aC2); aD2 = fmaf(wd, bf2f(hd.z), aD2);
        aA3 = fmaf(wa, bf2f(ha.w), aA3); aB3 = fmaf(wb, bf2f(hb.w), aB3);
        aC3 = fmaf(wc, bf2f(hc.w), aC3); aD3 = fmaf(wd, bf2f(hd.w), aD3);
    }
    for (; i < end; ++i) {
        float wa = exp2f(plane[i] - m);
        int sa = srcc[i];
        ushort4 ha = *(const ushort4*)(h + (size_t)sa * 256 + lane * 4);
        aA0 = fmaf(wa, bf2f(ha.x), aA0);
        aA1 = fmaf(wa, bf2f(ha.y), aA1);
        aA2 = fmaf(wa, bf2f(ha.z), aA2);
        aA3 = fmaf(wa, bf2f(ha.w), aA3);
    }

    float4 b4 = *(const float4*)(bias + lane * 4);
    float o0 = ((aA0 + aB0) + (aC0 + aD0)) * r + b4.x;
    float o1 = ((aA1 + aB1) + (aC1 + aD1)) * r + b4.y;
    float o2 = ((aA2 + aB2) + (aC2 + aD2)) * r + b4.z;
    float o3 = ((aA3 + aB3) + (aC3 + aD3)) * r + b4.w;
    if (do_relu) {
        o0 = fmaxf(o0, 0.f); o1 = fmaxf(o1, 0.f);
        o2 = fmaxf(o2, 0.f); o3 = fmaxf(o3, 0.f);
    }
    if (zero0 && wid == 0) { o0 = o1 = o2 = o3 = 0.f; }
    size_t base = (size_t)wid * 256 + lane * 4;
    if (outb) {
        ushort4 o; o.x = f2bf(o0); o.y = f2bf(o1); o.z = f2bf(o2); o.w = f2bf(o3);
        *(ushort4*)(outb + base) = o;
    } else {
        *(float4*)(outf + base) = make_float4(o0, o1, o2, o3);
    }
}

extern "C" void kernel_launch(void* const* d_in, const int* in_sizes, int n_in,
                              void* d_out, int out_size, void* d_ws, size_t ws_size,
                              hipStream_t stream)
{
    const float* emb = (const float*)d_in[0];
    const float* W0  = (const float*)d_in[1];
    const float* al0 = (const float*)d_in[2];
    const float* ar0 = (const float*)d_in[3];
    const float* b0  = (const float*)d_in[4];
    const float* W1  = (const float*)d_in[5];
    const float* al1 = (const float*)d_in[6];
    const float* ar1 = (const float*)d_in[7];
    const float* b1  = (const float*)d_in[8];
    const int* src   = (const int*)d_in[9];
    const int* dst   = (const int*)d_in[10];
    const int N = in_sizes[0] / 128;     // 50000
    const int E = in_sizes[9];           // 800000
    float* outp = (float*)d_out;

    char* w = (char*)d_ws;
    auto alloc = [&](size_t bytes) {
        char* p = w;
        w += (bytes + 255) & ~(size_t)255;
        return p;
    };
    unsigned short* hb  = (unsigned short*)alloc((size_t)N * 256 * 2); // h bf16
    unsigned short* x1b = (unsigned short*)alloc((size_t)N * 256 * 2); // x1 bf16
    unsigned short* embb = x1b;   // alias: emb bf16 dead once gemm0 completes
    float* ecsr = (float*)alloc((size_t)E * 2 * 4);   // planar prescaled logits
    int* srcc   = (int*)alloc((size_t)E * 4);
    int* rowp   = (int*)alloc((size_t)(N + 1) * 4);
    float* el0  = (float*)alloc((size_t)N * 2 * 4);
    float* er0  = (float*)alloc((size_t)N * 2 * 4);
    float* el1  = (float*)alloc((size_t)N * 4);
    float* er1  = (float*)alloc((size_t)N * 4);
    int* cnt    = (int*)alloc((size_t)N * 4);
    int* cursor = (int*)alloc((size_t)N * 4);
    int* bsum   = (int*)alloc(1024 * 4);
    unsigned short* W0t = (unsigned short*)alloc(256 * 128 * 2);
    unsigned short* W1t = (unsigned short*)alloc(256 * 256 * 2);

    const int nbScan = (N + 1023) / 1024;                    // 49
    const int nbW = (128 * 256 + 256 * 256 + 255) / 256;     // 384
    const int nbE = (E + 255) / 256;                         // 3125
    const int nEmb = N * 128;
    const int nbEmb = (nEmb / 4 + 255) / 256;                // 6250
    const int nbG = ((N + 127) / 128) * 2;                   // 782 gemm0 blocks

    // CSR count + weight converts + emb convert (fused)
    hipMemsetAsync(cnt, 0, (size_t)N * 4, stream);
    conv_count<<<nbW + nbE + nbEmb, 256, 0, stream>>>(
        W0, W0t, W1, W1t, emb, embb, dst, cnt, nbW, nbE, E, nEmb);
    scan_partial<<<nbScan, 256, 0, stream>>>(cnt, bsum, N);
    scan_final<<<nbScan, 256, 0, stream>>>(cnt, bsum, rowp, cursor,
                                           el0, er0, N, nbScan, E);

    // --- layer 0 (H=2): gemm0 + CSR fill fused (independent work) ---
    gemm0_fill<<<nbG + nbE, 256, 0, stream>>>(
        embb, W0t, hb, al0, ar0, el0, er0, N, 256, 128, nbG,
        src, dst, cursor, srcc, E);
    agg_kernel<2><<<(N + 3) / 4, 256, 0, stream>>>(
        hb, el0, er0, ecsr, srcc, rowp, b0, nullptr, x1b, el1, er1, N, E, 1, 0);

    // --- layer 1 (H=1): out = agg + b1, row0 zeroed, fp32 out ---
    gemm_fused<1><<<dim3((N + 127) / 128, 2), 256, 0, stream>>>(
        x1b, W1t, hb, al1, ar1, el1, er1, N, 256, 256);
    agg_kernel<1><<<(N + 3) / 4, 256, 0, stream>>>(
        hb, el1, er1, ecsr, srcc, rowp, b1, outp, nullptr, nullptr, nullptr, N, E, 0, 1);
}

// Round 13
// 278.369 us; speedup vs baseline: 1.0398x; 1.0398x over previous
//
#include <hip/hip_runtime.h>

// ---------------------------------------------------------------------------
// GAT 2-layer forward, round 13 = R11 structure + scan_bsum eliminated
// (scan_final self-computes its block offset; verified in R12).
// Separate lean fill_kernel restored (R12's gemm0+fill fusion killed fill's
// occupancy: 80 VGPR + 32KB LDS -> 26% occ -> 90us; lesson: only fuse
// resource-similar work).
// ---------------------------------------------------------------------------

typedef __attribute__((ext_vector_type(8))) short short8v;   // 8 bf16
typedef __attribute__((ext_vector_type(4))) float f32x4;

#define LOG2E 1.4426950408889634f

__device__ inline unsigned short f2bf(float x) {
    union { float f; unsigned int u; } v; v.f = x;
    unsigned int r = v.u + 0x7fffu + ((v.u >> 16) & 1u);   // RNE
    return (unsigned short)(r >> 16);
}
__device__ inline float bf2f(unsigned short h) {
    union { unsigned int u; float f; } v; v.u = ((unsigned int)h) << 16;
    return v.f;
}

// ---------------- fused GEMM + el/er partial dots ----------------
// C[M][N] = A[M][K] @ Bt[N][K]^T, A bf16. Tile 128x128, BK=64, 256 thr, 4 waves.
template<int H>
__global__ __launch_bounds__(256) void gemm_fused(
    const unsigned short* __restrict__ A, const unsigned short* __restrict__ Bt,
    unsigned short* __restrict__ C,
    const float* __restrict__ al, const float* __restrict__ ar,
    float* __restrict__ el, float* __restrict__ er,
    int M, int N, int K)
{
    __shared__ __align__(16) unsigned short As[128 * 64];
    __shared__ __align__(16) unsigned short Bs[128 * 64];
    const int tid = threadIdx.x;
    const int lane = tid & 63, wv = tid >> 6;
    const int rowBase = blockIdx.x * 128;
    const int colBase = blockIdx.y * 128;

    f32x4 acc[2][8];
    #pragma unroll
    for (int i = 0; i < 2; ++i)
        #pragma unroll
        for (int j = 0; j < 8; ++j)
            acc[i][j] = (f32x4){0.f, 0.f, 0.f, 0.f};

    for (int k0 = 0; k0 < K; k0 += 64) {
        #pragma unroll
        for (int c = tid; c < 128 * 8; c += 256) {
            int row = c >> 3, cc = c & 7;
            int gr = rowBase + row; if (gr >= M) gr = M - 1;
            int4 v = *(const int4*)(A + (size_t)gr * K + k0 + cc * 8);
            *(int4*)&As[row * 64 + (cc ^ (row & 7)) * 8] = v;
        }
        #pragma unroll
        for (int c = tid; c < 128 * 8; c += 256) {
            int n2 = c >> 3, cc = c & 7;
            int4 v = *(const int4*)(Bt + (size_t)(colBase + n2) * K + k0 + cc * 8);
            *(int4*)&Bs[n2 * 64 + (cc ^ (n2 & 7)) * 8] = v;
        }
        __syncthreads();

        #pragma unroll
        for (int ks = 0; ks < 64; ks += 32) {
            int kchunk = (ks >> 3) + (lane >> 4);   // 0..7
            short8v af[2], bfr[8];
            #pragma unroll
            for (int fm = 0; fm < 2; ++fm) {
                int ml = wv * 32 + fm * 16 + (lane & 15);
                af[fm] = *(const short8v*)&As[ml * 64 + (kchunk ^ (ml & 7)) * 8];
            }
            #pragma unroll
            for (int fi = 0; fi < 8; ++fi) {
                int nl = fi * 16 + (lane & 15);
                bfr[fi] = *(const short8v*)&Bs[nl * 64 + (kchunk ^ (nl & 7)) * 8];
            }
            #pragma unroll
            for (int fm = 0; fm < 2; ++fm)
                #pragma unroll
                for (int fi = 0; fi < 8; ++fi)
                    acc[fm][fi] = __builtin_amdgcn_mfma_f32_16x16x32_bf16(
                        af[fm], bfr[fi], acc[fm][fi], 0, 0, 0);
        }
        __syncthreads();
    }

    float alv[8], arv[8];
    #pragma unroll
    for (int fi = 0; fi < 8; ++fi) {
        int col = colBase + fi * 16 + (lane & 15);
        alv[fi] = al[col];
        arv[fi] = ar[col];
    }
    const int head = (H == 2) ? (colBase >> 7) : 0;

    #pragma unroll
    for (int fm = 0; fm < 2; ++fm) {
        #pragma unroll
        for (int r = 0; r < 4; ++r) {
            int row = rowBase + wv * 32 + fm * 16 + (lane >> 4) * 4 + r;
            float pe = 0.f, pr2 = 0.f;
            #pragma unroll
            for (int fi = 0; fi < 8; ++fi) {
                pe  = fmaf(acc[fm][fi][r], alv[fi], pe);
                pr2 = fmaf(acc[fm][fi][r], arv[fi], pr2);
            }
            #pragma unroll
            for (int off = 8; off; off >>= 1) {
                pe  += __shfl_xor(pe, off);
                pr2 += __shfl_xor(pr2, off);
            }
            if (row < M) {
                #pragma unroll
                for (int fi = 0; fi < 8; ++fi) {
                    int col = colBase + fi * 16 + (lane & 15);
                    C[(size_t)row * N + col] = f2bf(acc[fm][fi][r]);
                }
                if ((lane & 15) == 0) {
                    atomicAdd(&el[row * H + head], pe);
                    atomicAdd(&er[row * H + head], pr2);
                }
            }
        }
    }
}

// ---------------- fused weight-convert + emb-convert + count ----------------
__global__ void conv_count(const float* __restrict__ W0, unsigned short* __restrict__ W0t,
                           const float* __restrict__ W1, unsigned short* __restrict__ W1t,
                           const float* __restrict__ emb, unsigned short* __restrict__ embb,
                           const int* __restrict__ dst, int* __restrict__ cnt,
                           int nbW, int nbE, int E, int nEmb)
{
    int bid = blockIdx.x;
    if (bid < nbW) {
        int t = bid * 256 + threadIdx.x;
        if (t < 128 * 256) {
            int k = t >> 8, n2 = t & 255;
            W0t[n2 * 128 + k] = f2bf(W0[t]);
        }
        int u = t - 128 * 256;
        if (u >= 0 && u < 256 * 256) {
            int k = u >> 8, n2 = u & 255;
            W1t[n2 * 256 + k] = f2bf(W1[u]);
        }
    } else if (bid < nbW + nbE) {
        int t = (bid - nbW) * 256 + threadIdx.x;
        if (t < E) atomicAdd(&cnt[dst[t]], 1);
    } else {
        int t = ((bid - nbW - nbE) * 256 + threadIdx.x) * 4;
        if (t + 3 < nEmb) {
            float4 v = *(const float4*)(emb + t);
            ushort4 o;
            o.x = f2bf(v.x); o.y = f2bf(v.y); o.z = f2bf(v.z); o.w = f2bf(v.w);
            *(ushort4*)(embb + t) = o;
        }
    }
}

__global__ __launch_bounds__(256) void scan_partial(const int* __restrict__ cnt,
                                                    int* __restrict__ bsum, int n)
{
    int t = threadIdx.x;
    int idx = blockIdx.x * 1024 + t * 4;
    int4 v = make_int4(0, 0, 0, 0);
    if (idx + 3 < n) v = *(const int4*)(cnt + idx);
    else if (idx < n) {
        v.x = cnt[idx];
        if (idx + 1 < n) v.y = cnt[idx + 1];
        if (idx + 2 < n) v.z = cnt[idx + 2];
    }
    int s = v.x + v.y + v.z + v.w;
    #pragma unroll
    for (int off = 32; off; off >>= 1) s += __shfl_xor(s, off);
    __shared__ int ws[4];
    if ((t & 63) == 0) ws[t >> 6] = s;
    __syncthreads();
    if (t == 0) bsum[blockIdx.x] = ws[0] + ws[1] + ws[2] + ws[3];
}

// scan_final: self-computes block offset from RAW bsum (wave-0 prefix scan),
// writes row/cursor, zeroes el0/er0, block 0 writes row[n]=E. [R12-verified]
__global__ __launch_bounds__(256) void scan_final(
    const int* __restrict__ cnt, const int* __restrict__ bsum,
    int* __restrict__ row, int* __restrict__ cursor,
    float* __restrict__ el0, float* __restrict__ er0,
    int n, int nb, int E)
{
    int t = threadIdx.x;
    int lane = t & 63;
    __shared__ int blockOff;
    if (t < 64) {
        int v = (t < nb) ? bsum[t] : 0;
        int x = v;
        #pragma unroll
        for (int off = 1; off < 64; off <<= 1) {
            int y = __shfl_up(x, off);
            if (lane >= off) x += y;
        }
        if (t == (int)blockIdx.x) blockOff = x - v;   // exclusive prefix
    }
    if (blockIdx.x == 0 && t == 0) row[n] = E;

    int idx = blockIdx.x * 1024 + t * 4;
    int4 v = make_int4(0, 0, 0, 0);
    if (idx + 3 < n) v = *(const int4*)(cnt + idx);
    else if (idx < n) {
        v.x = cnt[idx];
        if (idx + 1 < n) v.y = cnt[idx + 1];
        if (idx + 2 < n) v.z = cnt[idx + 2];
    }
    int s1 = v.x + v.y, s2 = s1 + v.z, s3 = s2 + v.w;
    int tsum = s3;
    int x = tsum;
    #pragma unroll
    for (int off = 1; off < 64; off <<= 1) {
        int y = __shfl_up(x, off);
        if (lane >= off) x += y;
    }
    int wex = x - tsum;
    __shared__ int ws[4];
    if (lane == 63) ws[t >> 6] = x;
    __syncthreads();
    int off0 = blockOff;
    for (int w2 = 0; w2 < (t >> 6); ++w2) off0 += ws[w2];
    int e0 = off0 + wex;
    float2 z2 = make_float2(0.f, 0.f);
    if (idx < n)     { row[idx]     = e0;        cursor[idx]     = e0;
                       *(float2*)(el0 + 2*idx)     = z2; *(float2*)(er0 + 2*idx)     = z2; }
    if (idx + 1 < n) { row[idx + 1] = e0 + v.x;  cursor[idx + 1] = e0 + v.x;
                       *(float2*)(el0 + 2*idx + 2) = z2; *(float2*)(er0 + 2*idx + 2) = z2; }
    if (idx + 2 < n) { row[idx + 2] = e0 + s1;   cursor[idx + 2] = e0 + s1;
                       *(float2*)(el0 + 2*idx + 4) = z2; *(float2*)(er0 + 2*idx + 4) = z2; }
    if (idx + 3 < n) { row[idx + 3] = e0 + s2;   cursor[idx + 3] = e0 + s2;
                       *(float2*)(el0 + 2*idx + 6) = z2; *(float2*)(er0 + 2*idx + 6) = z2; }
}

// lean fill: CSR-ordered src (low VGPR, no LDS -> full occupancy)
__global__ void fill_kernel(const int* __restrict__ src, const int* __restrict__ dst,
                            int* __restrict__ cursor, int* __restrict__ srcc, int E)
{
    int t = blockIdx.x * blockDim.x + threadIdx.x;
    if (t < E) {
        int pos = atomicAdd(&cursor[dst[t]], 1);
        srcc[pos] = src[t];
    }
}

// ---------------- per-dst-node softmax + weighted gather (R8 structure) ------
template<int H>
__global__ __launch_bounds__(256) void agg_kernel(
    const unsigned short* __restrict__ h, const float* __restrict__ el,
    const float* __restrict__ er, float* __restrict__ ecsr,
    const int* __restrict__ srcc, const int* __restrict__ row,
    const float* __restrict__ bias, float* __restrict__ outf,
    unsigned short* __restrict__ outb,
    float* __restrict__ elz, float* __restrict__ erz,
    int n_nodes, int E, int do_relu, int zero0)
{
    int wid = blockIdx.x * 4 + (threadIdx.x >> 6);
    if (wid >= n_nodes) return;
    int lane = threadIdx.x & 63;
    int beg = __builtin_amdgcn_readfirstlane(row[wid]);
    int end = __builtin_amdgcn_readfirstlane(row[wid + 1]);
    const int hsel   = (H == 2) ? (lane >> 5) : 0;
    const int stride = (H == 2) ? 32 : 64;
    const int l0     = (H == 2) ? (lane & 31) : lane;
    float* plane = ecsr + (size_t)hsel * E;
    const float rr = er[wid * H + hsel];

    if (elz && lane == 0) { elz[wid] = 0.f; erz[wid] = 0.f; }

    // stats pass: gather el[src], leaky, prescale by log2e, write plane, online m/s
    float m = -1e30f, s = 0.f;
    for (int i = beg + l0; i < end; i += stride) {
        int sn = srcc[i];
        float v = el[sn * H + hsel] + rr;
        float ev = ((v > 0.f) ? v : 0.2f * v) * LOG2E;
        plane[i] = ev;
        float mn = fmaxf(m, ev);
        s = s * exp2f(m - mn) + exp2f(ev - mn);
        m = mn;
    }
    #pragma unroll
    for (int off = (H == 2) ? 16 : 32; off; off >>= 1) {
        float mo = __shfl_xor(m, off);
        float so = __shfl_xor(s, off);
        float mn = fmaxf(m, mo);
        s = s * exp2f(m - mn) + so * exp2f(mo - mn);
        m = mn;
    }
    float r = (s > 0.f) ? 1.f / s : 0.f;
    __threadfence_block();

    // un-normalized weighted gather (x 1/s at the end), unroll 4
    float aA0 = 0.f, aA1 = 0.f, aA2 = 0.f, aA3 = 0.f;
    float aB0 = 0.f, aB1 = 0.f, aB2 = 0.f, aB3 = 0.f;
    float aC0 = 0.f, aC1 = 0.f, aC2 = 0.f, aC3 = 0.f;
    float aD0 = 0.f, aD1 = 0.f, aD2 = 0.f, aD3 = 0.f;
    int i = beg;
    for (; i + 3 < end; i += 4) {
        float wa = exp2f(plane[i]     - m);
        float wb = exp2f(plane[i + 1] - m);
        float wc = exp2f(plane[i + 2] - m);
        float wd = exp2f(plane[i + 3] - m);
        int sa = srcc[i], sb = srcc[i + 1], sc2 = srcc[i + 2], sd = srcc[i + 3];
        ushort4 ha = *(const ushort4*)(h + (size_t)sa * 256 + lane * 4);
        ushort4 hb = *(const ushort4*)(h + (size_t)sb * 256 + lane * 4);
        ushort4 hc = *(const ushort4*)(h + (size_t)sc2 * 256 + lane * 4);
        ushort4 hd = *(const ushort4*)(h + (size_t)sd * 256 + lane * 4);
        aA0 = fmaf(wa, bf2f(ha.x), aA0); aB0 = fmaf(wb, bf2f(hb.x), aB0);
        aC0 = fmaf(wc, bf2f(hc.x), aC0); aD0 = fmaf(wd, bf2f(hd.x), aD0);
        aA1 = fmaf(wa, bf2f(ha.y), aA1); aB1 = fmaf(wb, bf2f(hb.y), aB1);
        aC1 = fmaf(wc, bf2f(hc.y), aC1); aD1 = fmaf(wd, bf2f(hd.y), aD1);
        aA2 = fmaf(wa, bf2f(ha.z), aA2); aB2 = fmaf(wb, bf2f(hb.z), aB2);
        aC2 = fmaf(wc, bf2f(hc.z), aC2); aD2 = fmaf(wd, bf2f(hd.z), aD2);
        aA3 = fmaf(wa, bf2f(ha.w), aA3); aB3 = fmaf(wb, bf2f(hb.w), aB3);
        aC3 = fmaf(wc, bf2f(hc.w), aC3); aD3 = fmaf(wd, bf2f(hd.w), aD3);
    }
    for (; i < end; ++i) {
        float wa = exp2f(plane[i] - m);
        int sa = srcc[i];
        ushort4 ha = *(const ushort4*)(h + (size_t)sa * 256 + lane * 4);
        aA0 = fmaf(wa, bf2f(ha.x), aA0);
        aA1 = fmaf(wa, bf2f(ha.y), aA1);
        aA2 = fmaf(wa, bf2f(ha.z), aA2);
        aA3 = fmaf(wa, bf2f(ha.w), aA3);
    }

    float4 b4 = *(const float4*)(bias + lane * 4);
    float o0 = ((aA0 + aB0) + (aC0 + aD0)) * r + b4.x;
    float o1 = ((aA1 + aB1) + (aC1 + aD1)) * r + b4.y;
    float o2 = ((aA2 + aB2) + (aC2 + aD2)) * r + b4.z;
    float o3 = ((aA3 + aB3) + (aC3 + aD3)) * r + b4.w;
    if (do_relu) {
        o0 = fmaxf(o0, 0.f); o1 = fmaxf(o1, 0.f);
        o2 = fmaxf(o2, 0.f); o3 = fmaxf(o3, 0.f);
    }
    if (zero0 && wid == 0) { o0 = o1 = o2 = o3 = 0.f; }
    size_t base = (size_t)wid * 256 + lane * 4;
    if (outb) {
        ushort4 o; o.x = f2bf(o0); o.y = f2bf(o1); o.z = f2bf(o2); o.w = f2bf(o3);
        *(ushort4*)(outb + base) = o;
    } else {
        *(float4*)(outf + base) = make_float4(o0, o1, o2, o3);
    }
}

extern "C" void kernel_launch(void* const* d_in, const int* in_sizes, int n_in,
                              void* d_out, int out_size, void* d_ws, size_t ws_size,
                              hipStream_t stream)
{
    const float* emb = (const float*)d_in[0];
    const float* W0  = (const float*)d_in[1];
    const float* al0 = (const float*)d_in[2];
    const float* ar0 = (const float*)d_in[3];
    const float* b0  = (const float*)d_in[4];
    const float* W1  = (const float*)d_in[5];
    const float* al1 = (const float*)d_in[6];
    const float* ar1 = (const float*)d_in[7];
    const float* b1  = (const float*)d_in[8];
    const int* src   = (const int*)d_in[9];
    const int* dst   = (const int*)d_in[10];
    const int N = in_sizes[0] / 128;     // 50000
    const int E = in_sizes[9];           // 800000
    float* outp = (float*)d_out;

    char* w = (char*)d_ws;
    auto alloc = [&](size_t bytes) {
        char* p = w;
        w += (bytes + 255) & ~(size_t)255;
        return p;
    };
    unsigned short* hb  = (unsigned short*)alloc((size_t)N * 256 * 2); // h bf16
    unsigned short* x1b = (unsigned short*)alloc((size_t)N * 256 * 2); // x1 bf16
    unsigned short* embb = x1b;   // alias: emb bf16 dead once gemm0 completes
    float* ecsr = (float*)alloc((size_t)E * 2 * 4);   // planar prescaled logits
    int* srcc   = (int*)alloc((size_t)E * 4);
    int* rowp   = (int*)alloc((size_t)(N + 1) * 4);
    float* el0  = (float*)alloc((size_t)N * 2 * 4);
    float* er0  = (float*)alloc((size_t)N * 2 * 4);
    float* el1  = (float*)alloc((size_t)N * 4);
    float* er1  = (float*)alloc((size_t)N * 4);
    int* cnt    = (int*)alloc((size_t)N * 4);
    int* cursor = (int*)alloc((size_t)N * 4);
    int* bsum   = (int*)alloc(1024 * 4);
    unsigned short* W0t = (unsigned short*)alloc(256 * 128 * 2);
    unsigned short* W1t = (unsigned short*)alloc(256 * 256 * 2);

    const int nbScan = (N + 1023) / 1024;                    // 49
    const int nbW = (128 * 256 + 256 * 256 + 255) / 256;     // 384
    const int nbE = (E + 255) / 256;                         // 3125
    const int nEmb = N * 128;
    const int nbEmb = (nEmb / 4 + 255) / 256;                // 6250

    // CSR count + weight converts + emb convert (fused)
    hipMemsetAsync(cnt, 0, (size_t)N * 4, stream);
    conv_count<<<nbW + nbE + nbEmb, 256, 0, stream>>>(
        W0, W0t, W1, W1t, emb, embb, dst, cnt, nbW, nbE, E, nEmb);
    scan_partial<<<nbScan, 256, 0, stream>>>(cnt, bsum, N);
    scan_final<<<nbScan, 256, 0, stream>>>(cnt, bsum, rowp, cursor,
                                           el0, er0, N, nbScan, E);
    fill_kernel<<<nbE, 256, 0, stream>>>(src, dst, cursor, srcc, E);

    // --- layer 0 (H=2): x1 = relu(agg + b0) -> bf16 x1b; zeroes el1/er1 ---
    gemm_fused<2><<<dim3((N + 127) / 128, 2), 256, 0, stream>>>(
        embb, W0t, hb, al0, ar0, el0, er0, N, 256, 128);
    agg_kernel<2><<<(N + 3) / 4, 256, 0, stream>>>(
        hb, el0, er0, ecsr, srcc, rowp, b0, nullptr, x1b, el1, er1, N, E, 1, 0);

    // --- layer 1 (H=1): out = agg + b1, row0 zeroed, fp32 out ---
    gemm_fused<1><<<dim3((N + 127) / 128, 2), 256, 0, stream>>>(
        x1b, W1t, hb, al1, ar1, el1, er1, N, 256, 256);
    agg_kernel<1><<<(N + 3) / 4, 256, 0, stream>>>(
        hb, el1, er1, ecsr, srcc, rowp, b1, outp, nullptr, nullptr, nullptr, N, E, 0, 1);
}